// Round 1
// baseline (608.039 us; speedup 1.0000x reference)
//
#include <hip/hip_runtime.h>
#include <cmath>

#define NB    16
#define TT1   2048
#define TT2   512
#define NMEL  80
#define NTEXT 256
#define NATT  256
#define TEMP  0.0005f

// workspace layout (floats)
#define KP_SZ   (NB*514*256)        // padded keys (B, 514, 256)
#define H1_SZ   (NB*512*512)        // key conv1 out (relu)
#define KE_SZ   (NB*512*256)        // key proj out
#define K2_SZ   (NB*512)            // |ke|^2 per (b,t2)
#define QP_SZ   (NB*2050*80)        // padded transposed queries (B, 2050, 80)
#define QH1_SZ  (NB*2048*160)
#define QH2_SZ  (NB*2048*80)
#define QE_SZ   (NB*2048*256)

// ---------------- padding / transpose ----------------

__global__ void pad_keys_kernel(const float* __restrict__ keys, float* __restrict__ kp) {
    int idx = blockIdx.x * blockDim.x + threadIdx.x;
    int total = KP_SZ;
    if (idx >= total) return;
    int c = idx & 255;
    int r = (idx >> 8) % 514;
    int b = idx / (514 * 256);
    float v = 0.f;
    if (r >= 1 && r <= 512)
        v = keys[((size_t)b * 512 + (r - 1)) * 256 + c];
    kp[idx] = v;
}

__global__ void pad_transpose_queries_kernel(const float* __restrict__ q, float* __restrict__ qp) {
    int idx = blockIdx.x * blockDim.x + threadIdx.x;
    int total = QP_SZ;
    if (idx >= total) return;
    int c = idx % 80;
    int r = (idx / 80) % 2050;
    int b = idx / (2050 * 80);
    float v = 0.f;
    if (r >= 1 && r <= 2048)
        v = q[((size_t)b * 80 + c) * 2048 + (r - 1)];
    qp[idx] = v;
}

// ---------------- generic conv-as-GEMM (fp32, 64x64 tile) ----------------
// C[m, n] = act( sum_k Arow(m)[k] * W[k*N + n] + bias[n] )
// Arow(m) = A + (m / Tdim)*bStride + (m % Tdim)*rowStride   (K contiguous floats)

template<int K, int N, bool RELU>
__global__ __launch_bounds__(256) void conv_gemm(
    const float* __restrict__ A, const float* __restrict__ W,
    const float* __restrict__ bias, float* __restrict__ C,
    int Tdim, int bStride, int rowStride)
{
    __shared__ float As[16][64];
    __shared__ float Bs[16][64];
    const int m0 = blockIdx.x * 64;
    const int n0 = blockIdx.y * 64;
    const int tid = threadIdx.x;
    const int tx = tid & 15;        // n micro
    const int ty = tid >> 4;        // m micro
    // A staging indices
    const int mL  = tid & 63;
    const int kk0 = (tid >> 6) << 2;    // 0,4,8,12
    const int m   = m0 + mL;
    const float* arow = A + (size_t)(m / Tdim) * bStride + (size_t)(m % Tdim) * rowStride;
    // B staging indices
    const int bkk = tid >> 4;           // 0..15
    const int bn  = (tid & 15) << 2;    // 0..60

    float acc[4][4];
    #pragma unroll
    for (int i = 0; i < 4; ++i)
        #pragma unroll
        for (int j = 0; j < 4; ++j) acc[i][j] = 0.f;

    for (int k0 = 0; k0 < K; k0 += 16) {
        float4 av = *(const float4*)(arow + k0 + kk0);
        As[kk0 + 0][mL] = av.x;
        As[kk0 + 1][mL] = av.y;
        As[kk0 + 2][mL] = av.z;
        As[kk0 + 3][mL] = av.w;
        int col = n0 + bn;
        float4 wv = make_float4(0.f, 0.f, 0.f, 0.f);
        if (col < N) wv = *(const float4*)(W + (size_t)(k0 + bkk) * N + col);
        *(float4*)&Bs[bkk][bn] = wv;
        __syncthreads();
        #pragma unroll
        for (int kk = 0; kk < 16; ++kk) {
            const float4 a4 = *(const float4*)&As[kk][ty << 2];
            const float4 b4 = *(const float4*)&Bs[kk][tx << 2];
            const float a[4] = {a4.x, a4.y, a4.z, a4.w};
            const float bb[4] = {b4.x, b4.y, b4.z, b4.w};
            #pragma unroll
            for (int i = 0; i < 4; ++i)
                #pragma unroll
                for (int j = 0; j < 4; ++j)
                    acc[i][j] = fmaf(a[i], bb[j], acc[i][j]);
        }
        __syncthreads();
    }

    const int col = n0 + (tx << 2);
    if (col < N) {
        const float4 bv = *(const float4*)(bias + col);
        #pragma unroll
        for (int i = 0; i < 4; ++i) {
            const int gm = m0 + (ty << 2) + i;
            float4 o;
            o.x = acc[i][0] + bv.x;
            o.y = acc[i][1] + bv.y;
            o.z = acc[i][2] + bv.z;
            o.w = acc[i][3] + bv.w;
            if (RELU) {
                o.x = fmaxf(o.x, 0.f); o.y = fmaxf(o.y, 0.f);
                o.z = fmaxf(o.z, 0.f); o.w = fmaxf(o.w, 0.f);
            }
            *(float4*)(C + (size_t)gm * N + col) = o;
        }
    }
}

// ---------------- k2 = sum(ke^2) over channels ----------------

__global__ void k2_kernel(const float* __restrict__ ke, float* __restrict__ k2) {
    int row = blockIdx.x * 4 + (threadIdx.x >> 6);   // (b*512 + t2)
    int lane = threadIdx.x & 63;
    float4 v = ((const float4*)(ke + (size_t)row * 256))[lane];
    float ss = v.x * v.x + v.y * v.y + v.z * v.z + v.w * v.w;
    #pragma unroll
    for (int off = 32; off; off >>= 1) ss += __shfl_xor(ss, off);
    if (lane == 0) k2[row] = ss;
}

// ---------------- fused attention (QK, log_softmax + prior, masked softmax) ----------------
// block: 512 threads = one (b, 16 t1 rows) tile; thread t owns t2 = t.

__device__ inline float wave_max64(float v) {
    #pragma unroll
    for (int off = 32; off; off >>= 1) v = fmaxf(v, __shfl_xor(v, off));
    return v;
}
__device__ inline float wave_sum64(float v) {
    #pragma unroll
    for (int off = 32; off; off >>= 1) v += __shfl_xor(v, off);
    return v;
}

__global__ __launch_bounds__(512) void attn_kernel(
    const float* __restrict__ qe, const float* __restrict__ ke,
    const float* __restrict__ k2, const float* __restrict__ prior,
    const unsigned char* __restrict__ mask,
    float* __restrict__ out_attn, float* __restrict__ out_lp)
{
    __shared__ float qs[16][NATT];
    __shared__ float red[16][8];
    const int b    = blockIdx.x >> 7;           // T1/16 = 128 tiles per b
    const int t1_0 = (blockIdx.x & 127) << 4;
    const int tid  = threadIdx.x;
    const int lane = tid & 63;
    const int wv   = tid >> 6;

    // stage qe tile (16 x 256 floats)
    for (int e = tid; e < 16 * NATT / 4; e += 512) {
        int r  = e >> 6;       // /64 float4 per row
        int c4 = e & 63;
        ((float4*)qs[r])[c4] =
            ((const float4*)(qe + ((size_t)b * TT1 + t1_0 + r) * NATT))[c4];
    }
    __syncthreads();

    const int t2 = tid;
    const float* krow = ke + ((size_t)b * TT2 + t2) * NATT;

    float acc[16];
    #pragma unroll
    for (int r = 0; r < 16; ++r) acc[r] = 0.f;

    for (int k = 0; k < NATT; k += 4) {
        const float4 kv = *(const float4*)(krow + k);
        #pragma unroll
        for (int r = 0; r < 16; ++r) {
            const float4 qv = *(const float4*)&qs[r][k];
            float a = acc[r];
            a = fmaf(kv.x, qv.x, a);
            a = fmaf(kv.y, qv.y, a);
            a = fmaf(kv.z, qv.z, a);
            a = fmaf(kv.w, qv.w, a);
            acc[r] = a;
        }
    }

    // s = -TEMP*(k2 - 2*qk)   (q2 term cancels in log_softmax/softmax)
    const float k2v = k2[(size_t)b * TT2 + t2];
    float s[16];
    #pragma unroll
    for (int r = 0; r < 16; ++r)
        s[r] = fmaf(2.0f * TEMP, acc[r], -TEMP * k2v);

    // ---- log_softmax over t2 (across all 512 threads) ----
    float rm[16];
    #pragma unroll
    for (int r = 0; r < 16; ++r) {
        float v = wave_max64(s[r]);
        if (lane == 0) red[r][wv] = v;
    }
    __syncthreads();
    #pragma unroll
    for (int r = 0; r < 16; ++r) {
        float mx = red[r][0];
        #pragma unroll
        for (int w = 1; w < 8; ++w) mx = fmaxf(mx, red[r][w]);
        rm[r] = mx;
    }
    __syncthreads();
    #pragma unroll
    for (int r = 0; r < 16; ++r) {
        float v = wave_sum64(expf(s[r] - rm[r]));
        if (lane == 0) red[r][wv] = v;
    }
    __syncthreads();
    float lp[16];
    {
        // prior row: prior[b, t2, t1_0 .. t1_0+16)
        const float* prow = prior + ((size_t)b * TT2 + t2) * TT1 + t1_0;
        float pv[16];
        #pragma unroll
        for (int i = 0; i < 16; i += 4) {
            float4 p4 = *(const float4*)(prow + i);
            pv[i + 0] = p4.x; pv[i + 1] = p4.y; pv[i + 2] = p4.z; pv[i + 3] = p4.w;
        }
        #pragma unroll
        for (int r = 0; r < 16; ++r) {
            float sm = 0.f;
            #pragma unroll
            for (int w = 0; w < 8; ++w) sm += red[r][w];
            const float logZ = rm[r] + logf(sm);
            lp[r] = s[r] - logZ + logf(pv[r] + 1e-8f);
        }
    }
    // store logprob (output 1)
    #pragma unroll
    for (int r = 0; r < 16; ++r)
        out_lp[((size_t)b * TT1 + t1_0 + r) * TT2 + t2] = lp[r];

    __syncthreads();   // red reuse

    // ---- masked softmax over t2 ----
    const bool mv = mask[(size_t)b * TT2 + t2] != 0;
    float s2[16];
    #pragma unroll
    for (int r = 0; r < 16; ++r) s2[r] = mv ? -INFINITY : lp[r];

    #pragma unroll
    for (int r = 0; r < 16; ++r) {
        float v = wave_max64(s2[r]);
        if (lane == 0) red[r][wv] = v;
    }
    __syncthreads();
    float rm2[16];
    #pragma unroll
    for (int r = 0; r < 16; ++r) {
        float mx = red[r][0];
        #pragma unroll
        for (int w = 1; w < 8; ++w) mx = fmaxf(mx, red[r][w]);
        rm2[r] = mx;
    }
    __syncthreads();
    float e2[16];
    #pragma unroll
    for (int r = 0; r < 16; ++r) {
        e2[r] = expf(s2[r] - rm2[r]);    // masked: exp(-inf) = 0
        float v = wave_sum64(e2[r]);
        if (lane == 0) red[r][wv] = v;
    }
    __syncthreads();
    #pragma unroll
    for (int r = 0; r < 16; ++r) {
        float sm = 0.f;
        #pragma unroll
        for (int w = 0; w < 8; ++w) sm += red[r][w];
        out_attn[((size_t)b * TT1 + t1_0 + r) * TT2 + t2] = e2[r] / sm;
    }
}

// ---------------- launch ----------------

extern "C" void kernel_launch(void* const* d_in, const int* in_sizes, int n_in,
                              void* d_out, int out_size, void* d_ws, size_t ws_size,
                              hipStream_t stream) {
    const float* queries = (const float*)d_in[0];   // (B, 80, 2048)
    const float* keys    = (const float*)d_in[1];   // (B, 512, 256)
    const unsigned char* mask = (const unsigned char*)d_in[2]; // (B, 512) bool
    const float* prior   = (const float*)d_in[3];   // (B, 512, 2048)
    const float* kw1 = (const float*)d_in[4];
    const float* kb1 = (const float*)d_in[5];
    const float* kw2 = (const float*)d_in[6];
    const float* kb2 = (const float*)d_in[7];
    const float* qw1 = (const float*)d_in[8];
    const float* qb1 = (const float*)d_in[9];
    const float* qw2 = (const float*)d_in[10];
    const float* qb2 = (const float*)d_in[11];
    const float* qw3 = (const float*)d_in[12];
    const float* qb3 = (const float*)d_in[13];

    float* ws  = (float*)d_ws;
    float* kp  = ws;
    float* h1  = kp  + KP_SZ;
    float* ke  = h1  + H1_SZ;
    float* k2  = ke  + KE_SZ;
    float* qp  = k2  + K2_SZ;
    float* qh1 = qp  + QP_SZ;
    float* qh2 = qh1 + QH1_SZ;
    float* qe  = qh2 + QH2_SZ;

    float* out_attn = (float*)d_out;
    float* out_lp   = out_attn + (size_t)NB * TT1 * TT2;

    // padding / transpose
    pad_keys_kernel<<<KP_SZ / 256, 256, 0, stream>>>(keys, kp);
    pad_transpose_queries_kernel<<<QP_SZ / 256, 256, 0, stream>>>(queries, qp);

    // key path: conv(256->512, k3) + relu ; conv(512->256, k1)
    conv_gemm<768, 512, true><<<dim3((NB * 512) / 64, 8), 256, 0, stream>>>(
        kp, kw1, kb1, h1, 512, 514 * 256, 256);
    conv_gemm<512, 256, false><<<dim3((NB * 512) / 64, 4), 256, 0, stream>>>(
        h1, kw2, kb2, ke, 512, 512 * 512, 512);
    k2_kernel<<<(NB * 512) / 4, 256, 0, stream>>>(ke, k2);

    // query path: conv(80->160, k3)+relu ; conv(160->80, k1)+relu ; conv(80->256, k1)
    conv_gemm<240, 160, true><<<dim3((NB * 2048) / 64, 3), 256, 0, stream>>>(
        qp, qw1, qb1, qh1, 2048, 2050 * 80, 80);
    conv_gemm<160, 80, true><<<dim3((NB * 2048) / 64, 2), 256, 0, stream>>>(
        qh1, qw2, qb2, qh2, 2048, 2048 * 160, 160);
    conv_gemm<80, 256, false><<<dim3((NB * 2048) / 64, 4), 256, 0, stream>>>(
        qh2, qw3, qb3, qe, 2048, 2048 * 80, 80);

    // fused attention
    attn_kernel<<<NB * (TT1 / 16), 512, 0, stream>>>(
        qe, ke, k2, prior, mask, out_attn, out_lp);
}

// Round 2
// 490.826 us; speedup vs baseline: 1.2388x; 1.2388x over previous
//
#include <hip/hip_runtime.h>
#include <cmath>

#define NB    16
#define TT1   2048
#define TT2   512
#define NMEL  80
#define NTEXT 256
#define NATT  256
#define TEMP  0.0005f

// workspace layout
#define KP_SZ   (NB*514*256)        // padded keys (B, 514, 256) f32
#define H1_SZ   (NB*512*512)        // key conv1 out (relu) f32
#define KE_SZ   (NB*512*256)        // key proj out (bf16, ushort)
#define K2_SZ   (NB*512)            // |ke|^2 per (b,t2) f32
#define QP_SZ   (NB*2050*80)        // padded transposed queries f32
#define QH1_SZ  (NB*2048*160)       // f32
#define QH2_SZ  (NB*2048*80)        // f32
#define QE_SZ   (NB*2048*256)       // qe (bf16, ushort)

typedef __attribute__((ext_vector_type(8))) short short8v;
typedef __attribute__((ext_vector_type(4))) float f32x4;

__device__ inline ushort f2bf(float f) {
    unsigned int u = __float_as_uint(f);
    u += 0x7fff + ((u >> 16) & 1);      // RNE
    return (ushort)(u >> 16);
}
__device__ inline float bf2f(ushort u) {
    return __uint_as_float(((unsigned int)u) << 16);
}

// ---------------- padding / transpose ----------------

__global__ void pad_keys_kernel(const float* __restrict__ keys, float* __restrict__ kp) {
    int idx = blockIdx.x * blockDim.x + threadIdx.x;
    if (idx >= KP_SZ) return;
    int c = idx & 255;
    int r = (idx >> 8) % 514;
    int b = idx / (514 * 256);
    float v = 0.f;
    if (r >= 1 && r <= 512)
        v = keys[((size_t)b * 512 + (r - 1)) * 256 + c];
    kp[idx] = v;
}

__global__ void pad_transpose_queries_kernel(const float* __restrict__ q, float* __restrict__ qp) {
    int idx = blockIdx.x * blockDim.x + threadIdx.x;
    if (idx >= QP_SZ) return;
    int c = idx % 80;
    int r = (idx / 80) % 2050;
    int b = idx / (2050 * 80);
    float v = 0.f;
    if (r >= 1 && r <= 2048)
        v = q[((size_t)b * 80 + c) * 2048 + (r - 1)];
    qp[idx] = v;
}

// ---------------- generic conv-as-GEMM (fp32 accum, 64x64 tile) ----------------
// OUT: 0 = fp32 C, 1 = bf16 C
// C[m, n] = act( sum_k Arow(m)[k] * W[k*N + n] + bias[n] )

template<int K, int N, bool RELU, int OUT>
__global__ __launch_bounds__(256) void conv_gemm(
    const float* __restrict__ A, const float* __restrict__ W,
    const float* __restrict__ bias, float* __restrict__ C, ushort* __restrict__ Cb,
    int Tdim, int bStride, int rowStride)
{
    __shared__ float As[16][64];
    __shared__ float Bs[16][64];
    const int m0 = blockIdx.x * 64;
    const int n0 = blockIdx.y * 64;
    const int tid = threadIdx.x;
    const int tx = tid & 15;
    const int ty = tid >> 4;
    const int mL  = tid & 63;
    const int kk0 = (tid >> 6) << 2;
    const int m   = m0 + mL;
    const float* arow = A + (size_t)(m / Tdim) * bStride + (size_t)(m % Tdim) * rowStride;
    const int bkk = tid >> 4;
    const int bn  = (tid & 15) << 2;

    float acc[4][4];
    #pragma unroll
    for (int i = 0; i < 4; ++i)
        #pragma unroll
        for (int j = 0; j < 4; ++j) acc[i][j] = 0.f;

    for (int k0 = 0; k0 < K; k0 += 16) {
        float4 av = *(const float4*)(arow + k0 + kk0);
        As[kk0 + 0][mL] = av.x;
        As[kk0 + 1][mL] = av.y;
        As[kk0 + 2][mL] = av.z;
        As[kk0 + 3][mL] = av.w;
        int col = n0 + bn;
        float4 wv = make_float4(0.f, 0.f, 0.f, 0.f);
        if (col < N) wv = *(const float4*)(W + (size_t)(k0 + bkk) * N + col);
        *(float4*)&Bs[bkk][bn] = wv;
        __syncthreads();
        #pragma unroll
        for (int kk = 0; kk < 16; ++kk) {
            const float4 a4 = *(const float4*)&As[kk][ty << 2];
            const float4 b4 = *(const float4*)&Bs[kk][tx << 2];
            const float a[4] = {a4.x, a4.y, a4.z, a4.w};
            const float bb[4] = {b4.x, b4.y, b4.z, b4.w};
            #pragma unroll
            for (int i = 0; i < 4; ++i)
                #pragma unroll
                for (int j = 0; j < 4; ++j)
                    acc[i][j] = fmaf(a[i], bb[j], acc[i][j]);
        }
        __syncthreads();
    }

    const int col = n0 + (tx << 2);
    if (col < N) {
        const float4 bv = *(const float4*)(bias + col);
        #pragma unroll
        for (int i = 0; i < 4; ++i) {
            const int gm = m0 + (ty << 2) + i;
            float4 o;
            o.x = acc[i][0] + bv.x;
            o.y = acc[i][1] + bv.y;
            o.z = acc[i][2] + bv.z;
            o.w = acc[i][3] + bv.w;
            if (RELU) {
                o.x = fmaxf(o.x, 0.f); o.y = fmaxf(o.y, 0.f);
                o.z = fmaxf(o.z, 0.f); o.w = fmaxf(o.w, 0.f);
            }
            if (OUT == 0) {
                *(float4*)(C + (size_t)gm * N + col) = o;
            } else {
                ushort4 st;
                st.x = f2bf(o.x); st.y = f2bf(o.y);
                st.z = f2bf(o.z); st.w = f2bf(o.w);
                *(ushort4*)(Cb + (size_t)gm * N + col) = st;
            }
        }
    }
}

// ---------------- k2 = sum(ke^2) over channels (bf16 input) ----------------

__global__ void k2_kernel(const ushort* __restrict__ ke, float* __restrict__ k2) {
    int row = blockIdx.x * 4 + (threadIdx.x >> 6);   // (b*512 + t2)
    int lane = threadIdx.x & 63;
    ushort4 v = ((const ushort4*)(ke + (size_t)row * 256))[lane];
    float x = bf2f(v.x), y = bf2f(v.y), z = bf2f(v.z), w = bf2f(v.w);
    float ss = x * x + y * y + z * z + w * w;
    #pragma unroll
    for (int off = 32; off; off >>= 1) ss += __shfl_xor(ss, off);
    if (lane == 0) k2[row] = ss;
}

// ---------------- fused attention ----------------
// block: 512 threads (8 waves) = one (b, 16 t1 rows) tile.
// phase 1: wave w computes S[0:16][w*64 : w*64+64] via bf16 MFMA -> LDS
// phase 2: thread t owns t2 = t; softmax pipeline (verified in round 1).

__device__ inline float wave_max64(float v) {
    #pragma unroll
    for (int off = 32; off; off >>= 1) v = fmaxf(v, __shfl_xor(v, off));
    return v;
}
__device__ inline float wave_sum64(float v) {
    #pragma unroll
    for (int off = 32; off; off >>= 1) v += __shfl_xor(v, off);
    return v;
}

__global__ __launch_bounds__(512) void attn_kernel(
    const ushort* __restrict__ qe, const ushort* __restrict__ ke,
    const float* __restrict__ k2, const float* __restrict__ prior,
    const unsigned char* __restrict__ mask,
    float* __restrict__ out_attn, float* __restrict__ out_lp)
{
    __shared__ float S[16][516];
    __shared__ float red[16][8];
    const int b    = blockIdx.x >> 7;           // 128 tiles per b
    const int t1_0 = (blockIdx.x & 127) << 4;
    const int tid  = threadIdx.x;
    const int lane = tid & 63;
    const int wv   = tid >> 6;

    // ---- phase 1: QK^T via MFMA ----
    {
        const int lr = lane & 15;     // fragment row/col
        const int lk = lane >> 4;     // k-group
        // A fragments: qe rows t1_0+lr, k = kstep*32 + lk*8 + [0..7]
        const ushort* qrow = qe + ((size_t)b * TT1 + t1_0 + lr) * NATT + lk * 8;
        short8v a[8];
        #pragma unroll
        for (int k = 0; k < 8; ++k)
            a[k] = *(const short8v*)(qrow + k * 32);

        const ushort* kbase = ke + ((size_t)b * TT2 + wv * 64 + lr) * NATT + lk * 8;
        #pragma unroll
        for (int n = 0; n < 4; ++n) {
            f32x4 acc = {0.f, 0.f, 0.f, 0.f};
            const ushort* kb = kbase + (size_t)n * 16 * NATT;
            #pragma unroll
            for (int k = 0; k < 8; ++k) {
                short8v bfr = *(const short8v*)(kb + k * 32);
                acc = __builtin_amdgcn_mfma_f32_16x16x32_bf16(a[k], bfr, acc, 0, 0, 0);
            }
            // C layout: col = lane&15, row = (lane>>4)*4 + reg
            #pragma unroll
            for (int r = 0; r < 4; ++r)
                S[lk * 4 + r][wv * 64 + n * 16 + lr] = acc[r];
        }
    }
    __syncthreads();

    // ---- phase 2: softmax pipeline ----
    const int t2 = tid;
    const float k2v = k2[(size_t)b * TT2 + t2];
    float s[16];
    #pragma unroll
    for (int r = 0; r < 16; ++r)
        s[r] = fmaf(2.0f * TEMP, S[r][t2], -TEMP * k2v);

    // log_softmax over t2
    float rm[16];
    #pragma unroll
    for (int r = 0; r < 16; ++r) {
        float v = wave_max64(s[r]);
        if (lane == 0) red[r][wv] = v;
    }
    __syncthreads();
    #pragma unroll
    for (int r = 0; r < 16; ++r) {
        float mx = red[r][0];
        #pragma unroll
        for (int w = 1; w < 8; ++w) mx = fmaxf(mx, red[r][w]);
        rm[r] = mx;
    }
    __syncthreads();
    #pragma unroll
    for (int r = 0; r < 16; ++r) {
        float v = wave_sum64(expf(s[r] - rm[r]));
        if (lane == 0) red[r][wv] = v;
    }
    __syncthreads();
    float lp[16];
    {
        const float* prow = prior + ((size_t)b * TT2 + t2) * TT1 + t1_0;
        float pv[16];
        #pragma unroll
        for (int i = 0; i < 16; i += 4) {
            float4 p4 = *(const float4*)(prow + i);
            pv[i + 0] = p4.x; pv[i + 1] = p4.y; pv[i + 2] = p4.z; pv[i + 3] = p4.w;
        }
        #pragma unroll
        for (int r = 0; r < 16; ++r) {
            float sm = 0.f;
            #pragma unroll
            for (int w = 0; w < 8; ++w) sm += red[r][w];
            const float logZ = rm[r] + logf(sm);
            lp[r] = s[r] - logZ + logf(pv[r] + 1e-8f);
        }
    }
    #pragma unroll
    for (int r = 0; r < 16; ++r)
        out_lp[((size_t)b * TT1 + t1_0 + r) * TT2 + t2] = lp[r];

    __syncthreads();

    // masked softmax over t2
    const bool mv = mask[(size_t)b * TT2 + t2] != 0;
    float s2[16];
    #pragma unroll
    for (int r = 0; r < 16; ++r) s2[r] = mv ? -INFINITY : lp[r];

    #pragma unroll
    for (int r = 0; r < 16; ++r) {
        float v = wave_max64(s2[r]);
        if (lane == 0) red[r][wv] = v;
    }
    __syncthreads();
    float rm2[16];
    #pragma unroll
    for (int r = 0; r < 16; ++r) {
        float mx = red[r][0];
        #pragma unroll
        for (int w = 1; w < 8; ++w) mx = fmaxf(mx, red[r][w]);
        rm2[r] = mx;
    }
    __syncthreads();
    float e2[16];
    #pragma unroll
    for (int r = 0; r < 16; ++r) {
        e2[r] = expf(s2[r] - rm2[r]);
        float v = wave_sum64(e2[r]);
        if (lane == 0) red[r][wv] = v;
    }
    __syncthreads();
    #pragma unroll
    for (int r = 0; r < 16; ++r) {
        float sm = 0.f;
        #pragma unroll
        for (int w = 0; w < 8; ++w) sm += red[r][w];
        out_attn[((size_t)b * TT1 + t1_0 + r) * TT2 + t2] = e2[r] / sm;
    }
}

// ---------------- launch ----------------

extern "C" void kernel_launch(void* const* d_in, const int* in_sizes, int n_in,
                              void* d_out, int out_size, void* d_ws, size_t ws_size,
                              hipStream_t stream) {
    const float* queries = (const float*)d_in[0];   // (B, 80, 2048)
    const float* keys    = (const float*)d_in[1];   // (B, 512, 256)
    const unsigned char* mask = (const unsigned char*)d_in[2]; // (B, 512) bool
    const float* prior   = (const float*)d_in[3];   // (B, 512, 2048)
    const float* kw1 = (const float*)d_in[4];
    const float* kb1 = (const float*)d_in[5];
    const float* kw2 = (const float*)d_in[6];
    const float* kb2 = (const float*)d_in[7];
    const float* qw1 = (const float*)d_in[8];
    const float* qb1 = (const float*)d_in[9];
    const float* qw2 = (const float*)d_in[10];
    const float* qb2 = (const float*)d_in[11];
    const float* qw3 = (const float*)d_in[12];
    const float* qb3 = (const float*)d_in[13];

    float* ws  = (float*)d_ws;
    float* kp  = ws;
    float* h1  = kp  + KP_SZ;
    ushort* ke_bf = (ushort*)(h1 + H1_SZ);
    float* k2  = (float*)(ke_bf + KE_SZ);
    float* qp  = k2  + K2_SZ;
    float* qh1 = qp  + QP_SZ;
    float* qh2 = qh1 + QH1_SZ;
    ushort* qe_bf = (ushort*)(qh2 + QH2_SZ);

    float* out_attn = (float*)d_out;
    float* out_lp   = out_attn + (size_t)NB * TT1 * TT2;

    // padding / transpose
    pad_keys_kernel<<<KP_SZ / 256, 256, 0, stream>>>(keys, kp);
    pad_transpose_queries_kernel<<<QP_SZ / 256, 256, 0, stream>>>(queries, qp);

    // key path: conv(256->512, k3) + relu ; conv(512->256, k1) -> bf16
    conv_gemm<768, 512, true, 0><<<dim3((NB * 512) / 64, 8), 256, 0, stream>>>(
        kp, kw1, kb1, h1, nullptr, 512, 514 * 256, 256);
    conv_gemm<512, 256, false, 1><<<dim3((NB * 512) / 64, 4), 256, 0, stream>>>(
        h1, kw2, kb2, nullptr, ke_bf, 512, 512 * 512, 512);
    k2_kernel<<<(NB * 512) / 4, 256, 0, stream>>>(ke_bf, k2);

    // query path: conv(80->160, k3)+relu ; conv(160->80, k1)+relu ; conv(80->256, k1) -> bf16
    conv_gemm<240, 160, true, 0><<<dim3((NB * 2048) / 64, 3), 256, 0, stream>>>(
        qp, qw1, qb1, qh1, nullptr, 2048, 2050 * 80, 80);
    conv_gemm<160, 80, true, 0><<<dim3((NB * 2048) / 64, 2), 256, 0, stream>>>(
        qh1, qw2, qb2, qh2, nullptr, 2048, 2048 * 160, 160);
    conv_gemm<80, 256, false, 1><<<dim3((NB * 2048) / 64, 4), 256, 0, stream>>>(
        qh2, qw3, qb3, nullptr, qe_bf, 2048, 2048 * 80, 80);

    // fused attention
    attn_kernel<<<NB * (TT1 / 16), 512, 0, stream>>>(
        qe_bf, ke_bf, k2, prior, mask, out_attn, out_lp);
}

// Round 5
// 349.499 us; speedup vs baseline: 1.7397x; 1.4044x over previous
//
#include <hip/hip_runtime.h>
#include <cmath>

#define NB    16
#define TT1   2048
#define TT2   512
#define NMEL  80
#define NTEXT 256
#define NATT  256
#define TEMP  0.0005f

// workspace layout
#define KP_SZ   (NB*514*256)        // padded keys (B, 514, 256) f32
#define H1_SZ   (NB*512*512)        // key conv1 out (relu) f32
#define KE_SZ   (NB*512*256)        // key proj out (bf16, ushort)
#define K2_SZ   (NB*512)            // -TEMP*|ke|^2 per (b,t2) f32
#define QP_SZ   (NB*2050*80)        // padded transposed queries f32
#define QH1_SZ  (NB*2048*160)       // f32
#define QH2_SZ  (NB*2048*80)        // f32
#define QE_SZ   (NB*2048*256)       // qe (bf16, ushort)

typedef __attribute__((ext_vector_type(8))) short short8v;
typedef __attribute__((ext_vector_type(4))) float f32x4;

__device__ inline ushort f2bf(float f) {
    unsigned int u = __float_as_uint(f);
    u += 0x7fff + ((u >> 16) & 1);      // RNE
    return (ushort)(u >> 16);
}
__device__ inline float bf2f(ushort u) {
    return __uint_as_float(((unsigned int)u) << 16);
}

// ---------------- padding / transpose ----------------

__global__ void pad_keys_kernel(const float* __restrict__ keys, float* __restrict__ kp) {
    int idx = blockIdx.x * blockDim.x + threadIdx.x;
    if (idx >= KP_SZ) return;
    int c = idx & 255;
    int r = (idx >> 8) % 514;
    int b = idx / (514 * 256);
    float v = 0.f;
    if (r >= 1 && r <= 512)
        v = keys[((size_t)b * 512 + (r - 1)) * 256 + c];
    kp[idx] = v;
}

__global__ void pad_transpose_queries_kernel(const float* __restrict__ q, float* __restrict__ qp) {
    int idx = blockIdx.x * blockDim.x + threadIdx.x;
    if (idx >= QP_SZ) return;
    int c = idx % 80;
    int r = (idx / 80) % 2050;
    int b = idx / (2050 * 80);
    float v = 0.f;
    if (r >= 1 && r <= 2048)
        v = q[((size_t)b * 80 + c) * 2048 + (r - 1)];
    qp[idx] = v;
}

// ---------------- generic conv-as-GEMM (fp32 accum, 64x64 tile) ----------------

template<int K, int N, bool RELU, int OUT>
__global__ __launch_bounds__(256) void conv_gemm(
    const float* __restrict__ A, const float* __restrict__ W,
    const float* __restrict__ bias, float* __restrict__ C, ushort* __restrict__ Cb,
    int Tdim, int bStride, int rowStride)
{
    __shared__ float As[16][64];
    __shared__ float Bs[16][64];
    const int m0 = blockIdx.x * 64;
    const int n0 = blockIdx.y * 64;
    const int tid = threadIdx.x;
    const int tx = tid & 15;
    const int ty = tid >> 4;
    const int mL  = tid & 63;
    const int kk0 = (tid >> 6) << 2;
    const int m   = m0 + mL;
    const float* arow = A + (size_t)(m / Tdim) * bStride + (size_t)(m % Tdim) * rowStride;
    const int bkk = tid >> 4;
    const int bn  = (tid & 15) << 2;

    float acc[4][4];
    #pragma unroll
    for (int i = 0; i < 4; ++i)
        #pragma unroll
        for (int j = 0; j < 4; ++j) acc[i][j] = 0.f;

    for (int k0 = 0; k0 < K; k0 += 16) {
        float4 av = *(const float4*)(arow + k0 + kk0);
        As[kk0 + 0][mL] = av.x;
        As[kk0 + 1][mL] = av.y;
        As[kk0 + 2][mL] = av.z;
        As[kk0 + 3][mL] = av.w;
        int col = n0 + bn;
        float4 wv = make_float4(0.f, 0.f, 0.f, 0.f);
        if (col < N) wv = *(const float4*)(W + (size_t)(k0 + bkk) * N + col);
        *(float4*)&Bs[bkk][bn] = wv;
        __syncthreads();
        #pragma unroll
        for (int kk = 0; kk < 16; ++kk) {
            const float4 a4 = *(const float4*)&As[kk][ty << 2];
            const float4 b4 = *(const float4*)&Bs[kk][tx << 2];
            const float a[4] = {a4.x, a4.y, a4.z, a4.w};
            const float bb[4] = {b4.x, b4.y, b4.z, b4.w};
            #pragma unroll
            for (int i = 0; i < 4; ++i)
                #pragma unroll
                for (int j = 0; j < 4; ++j)
                    acc[i][j] = fmaf(a[i], bb[j], acc[i][j]);
        }
        __syncthreads();
    }

    const int col = n0 + (tx << 2);
    if (col < N) {
        const float4 bv = *(const float4*)(bias + col);
        #pragma unroll
        for (int i = 0; i < 4; ++i) {
            const int gm = m0 + (ty << 2) + i;
            float4 o;
            o.x = acc[i][0] + bv.x;
            o.y = acc[i][1] + bv.y;
            o.z = acc[i][2] + bv.z;
            o.w = acc[i][3] + bv.w;
            if (RELU) {
                o.x = fmaxf(o.x, 0.f); o.y = fmaxf(o.y, 0.f);
                o.z = fmaxf(o.z, 0.f); o.w = fmaxf(o.w, 0.f);
            }
            if (OUT == 0) {
                *(float4*)(C + (size_t)gm * N + col) = o;
            } else {
                ushort4 st;
                st.x = f2bf(o.x); st.y = f2bf(o.y);
                st.z = f2bf(o.z); st.w = f2bf(o.w);
                *(ushort4*)(Cb + (size_t)gm * N + col) = st;
            }
        }
    }
}

// ---------------- k2t = -TEMP * sum(ke^2) (bf16 input) ----------------

__global__ void k2_kernel(const ushort* __restrict__ ke, float* __restrict__ k2) {
    int row = blockIdx.x * 4 + (threadIdx.x >> 6);   // (b*512 + t2)
    int lane = threadIdx.x & 63;
    ushort4 v = ((const ushort4*)(ke + (size_t)row * 256))[lane];
    float x = bf2f(v.x), y = bf2f(v.y), z = bf2f(v.z), w = bf2f(v.w);
    float ss = x * x + y * y + z * z + w * w;
    #pragma unroll
    for (int off = 32; off; off >>= 1) ss += __shfl_xor(ss, off);
    if (lane == 0) k2[row] = -TEMP * ss;
}

// ---------------- fused attention ----------------
// block: 512 threads (8 waves) = one (b, 16 t1 rows) tile.
// phase 1 : wave w computes s = 2*TEMP*QK^T + k2t for S[0:16][w*64..] -> LDS
// phase 2a: row-layout (32 thr/row) reduce -> logZ[r]
// phase 2b: t2-layout: u = s + log(prior), lp = u - logZ (store), U -> LDS (masked)
// phase 2c: row-layout reduce on U -> m2[r], inv[r]
// phase 2d: t2-layout: attn = exp(U - m2) * inv (store)

__global__ __launch_bounds__(512) void attn_kernel(
    const ushort* __restrict__ qe, const ushort* __restrict__ ke,
    const float* __restrict__ k2t, const float* __restrict__ prior,
    const unsigned char* __restrict__ mask,
    float* __restrict__ out_attn, float* __restrict__ out_lp)
{
    __shared__ float S[16][516];
    __shared__ float rowZ[16];   // logZ of first softmax
    __shared__ float rowM[16];   // masked max
    __shared__ float rowI[16];   // 1 / masked sumexp
    const int b    = blockIdx.x >> 7;           // 128 tiles per b
    const int t1_0 = (blockIdx.x & 127) << 4;
    const int tid  = threadIdx.x;
    const int lane = tid & 63;
    const int wv   = tid >> 6;

    // ---- phase 1: QK^T via MFMA, fold k2t ----
    {
        const int lr = lane & 15;
        const int lk = lane >> 4;
        const ushort* qrow = qe + ((size_t)b * TT1 + t1_0 + lr) * NATT + lk * 8;
        short8v a[8];
        #pragma unroll
        for (int k = 0; k < 8; ++k)
            a[k] = *(const short8v*)(qrow + k * 32);

        const ushort* kbase = ke + ((size_t)b * TT2 + wv * 64 + lr) * NATT + lk * 8;
        #pragma unroll
        for (int n = 0; n < 4; ++n) {
            f32x4 acc = {0.f, 0.f, 0.f, 0.f};
            const ushort* kb = kbase + (size_t)n * 16 * NATT;
            #pragma unroll
            for (int k = 0; k < 8; ++k) {
                short8v bfr = *(const short8v*)(kb + k * 32);
                acc = __builtin_amdgcn_mfma_f32_16x16x32_bf16(a[k], bfr, acc, 0, 0, 0);
            }
            const int col = wv * 64 + n * 16 + lr;          // t2 within tile
            const float k2v = k2t[(size_t)b * TT2 + col];
            #pragma unroll
            for (int r = 0; r < 4; ++r)
                S[lk * 4 + r][col] = fmaf(2.0f * TEMP, acc[r], k2v);
        }
    }
    __syncthreads();

    const int rr = tid >> 5;        // row-layout: row 0..15
    const int jj = tid & 31;        // 32 threads per row

    // ---- phase 2a: logZ per row ----
    {
        float sv[16];
        #pragma unroll
        for (int k = 0; k < 16; ++k) sv[k] = S[rr][jj + 32 * k];
        float mx = sv[0];
        #pragma unroll
        for (int k = 1; k < 16; ++k) mx = fmaxf(mx, sv[k]);
        #pragma unroll
        for (int off = 16; off; off >>= 1) mx = fmaxf(mx, __shfl_xor(mx, off));
        float se = 0.f;
        #pragma unroll
        for (int k = 0; k < 16; ++k) se += __expf(sv[k] - mx);
        #pragma unroll
        for (int off = 16; off; off >>= 1) se += __shfl_xor(se, off);
        if (jj == 0) rowZ[rr] = mx + __logf(se);
    }
    __syncthreads();

    // ---- phase 2b: lp store, U (masked) -> LDS ----
    const int t2 = tid;
    {
        const bool mv = mask[(size_t)b * TT2 + t2] != 0;
        const float* prow = prior + ((size_t)b * TT2 + t2) * TT1 + t1_0;
        #pragma unroll
        for (int g = 0; g < 4; ++g) {
            float4 p4 = ((const float4*)prow)[g];
            float pp[4] = {p4.x, p4.y, p4.z, p4.w};
            #pragma unroll
            for (int q = 0; q < 4; ++q) {
                const int r = g * 4 + q;
                const float sc = S[r][t2];
                const float uu = sc + __logf(pp[q] + 1e-8f);
                out_lp[((size_t)b * TT1 + t1_0 + r) * TT2 + t2] = uu - rowZ[r];
                S[r][t2] = mv ? -INFINITY : uu;
            }
        }
    }
    __syncthreads();

    // ---- phase 2c: masked max + inv-sumexp per row ----
    {
        float uv[16];
        #pragma unroll
        for (int k = 0; k < 16; ++k) uv[k] = S[rr][jj + 32 * k];
        float mx = uv[0];
        #pragma unroll
        for (int k = 1; k < 16; ++k) mx = fmaxf(mx, uv[k]);
        #pragma unroll
        for (int off = 16; off; off >>= 1) mx = fmaxf(mx, __shfl_xor(mx, off));
        float se = 0.f;
        #pragma unroll
        for (int k = 0; k < 16; ++k) se += __expf(uv[k] - mx);
        #pragma unroll
        for (int off = 16; off; off >>= 1) se += __shfl_xor(se, off);
        if (jj == 0) { rowM[rr] = mx; rowI[rr] = 1.0f / se; }
    }
    __syncthreads();

    // ---- phase 2d: attn = exp(U - m2) * inv ----
    #pragma unroll
    for (int r = 0; r < 16; ++r) {
        const float a = __expf(S[r][t2] - rowM[r]) * rowI[r];   // exp(-inf)=0 for masked
        out_attn[((size_t)b * TT1 + t1_0 + r) * TT2 + t2] = a;
    }
}

// ---------------- launch ----------------

extern "C" void kernel_launch(void* const* d_in, const int* in_sizes, int n_in,
                              void* d_out, int out_size, void* d_ws, size_t ws_size,
                              hipStream_t stream) {
    const float* queries = (const float*)d_in[0];   // (B, 80, 2048)
    const float* keys    = (const float*)d_in[1];   // (B, 512, 256)
    const unsigned char* mask = (const unsigned char*)d_in[2]; // (B, 512) bool
    const float* prior   = (const float*)d_in[3];   // (B, 512, 2048)
    const float* kw1 = (const float*)d_in[4];
    const float* kb1 = (const float*)d_in[5];
    const float* kw2 = (const float*)d_in[6];
    const float* kb2 = (const float*)d_in[7];
    const float* qw1 = (const float*)d_in[8];
    const float* qb1 = (const float*)d_in[9];
    const float* qw2 = (const float*)d_in[10];
    const float* qb2 = (const float*)d_in[11];
    const float* qw3 = (const float*)d_in[12];
    const float* qb3 = (const float*)d_in[13];

    float* ws  = (float*)d_ws;
    float* kp  = ws;
    float* h1  = kp  + KP_SZ;
    ushort* ke_bf = (ushort*)(h1 + H1_SZ);
    float* k2  = (float*)(ke_bf + KE_SZ);
    float* qp  = k2  + K2_SZ;
    float* qh1 = qp  + QP_SZ;
    float* qh2 = qh1 + QH1_SZ;
    ushort* qe_bf = (ushort*)(qh2 + QH2_SZ);

    float* out_attn = (float*)d_out;
    float* out_lp   = out_attn + (size_t)NB * TT1 * TT2;

    // padding / transpose
    pad_keys_kernel<<<KP_SZ / 256, 256, 0, stream>>>(keys, kp);
    pad_transpose_queries_kernel<<<QP_SZ / 256, 256, 0, stream>>>(queries, qp);

    // key path: conv(256->512, k3) + relu ; conv(512->256, k1) -> bf16
    conv_gemm<768, 512, true, 0><<<dim3((NB * 512) / 64, 8), 256, 0, stream>>>(
        kp, kw1, kb1, h1, nullptr, 512, 514 * 256, 256);
    conv_gemm<512, 256, false, 1><<<dim3((NB * 512) / 64, 4), 256, 0, stream>>>(
        h1, kw2, kb2, nullptr, ke_bf, 512, 512 * 512, 512);
    k2_kernel<<<(NB * 512) / 4, 256, 0, stream>>>(ke_bf, k2);

    // query path: conv(80->160, k3)+relu ; conv(160->80, k1)+relu ; conv(80->256, k1) -> bf16
    conv_gemm<240, 160, true, 0><<<dim3((NB * 2048) / 64, 3), 256, 0, stream>>>(
        qp, qw1, qb1, qh1, nullptr, 2048, 2050 * 80, 80);
    conv_gemm<160, 80, true, 0><<<dim3((NB * 2048) / 64, 2), 256, 0, stream>>>(
        qh1, qw2, qb2, qh2, nullptr, 2048, 2048 * 160, 160);
    conv_gemm<80, 256, false, 1><<<dim3((NB * 2048) / 64, 4), 256, 0, stream>>>(
        qh2, qw3, qb3, nullptr, qe_bf, 2048, 2048 * 80, 80);

    // fused attention
    attn_kernel<<<NB * (TT1 / 16), 512, 0, stream>>>(
        qe_bf, ke_bf, k2, prior, mask, out_attn, out_lp);
}

// Round 6
// 253.082 us; speedup vs baseline: 2.4025x; 1.3810x over previous
//
#include <hip/hip_runtime.h>
#include <cmath>

#define NB    16
#define TT1   2048
#define TT2   512
#define NATT  256
#define TEMP  0.0005f

// workspace element counts (ushort = bf16 unless noted)
#define KP_SZ   (NB*514*256)        // padded keys (B, 514, 256)
#define H1_SZ   (NB*512*512)        // key conv1 out (relu)
#define KE_SZ   (NB*512*256)        // key proj out
#define QP_SZ   (NB*2050*80)        // padded transposed queries
#define QH1_SZ  (NB*2048*160)
#define QH2_SZ  (NB*2048*80)
#define QE_SZ   (NB*2048*256)
#define W1T_SZ  (512*768)
#define W2T_SZ  (256*512)
#define W3T_SZ  (160*256)
#define W4T_SZ  (80*160)
#define W5T_SZ  (256*96)
#define K2_SZ   (NB*512)            // f32

typedef __attribute__((ext_vector_type(8))) short short8v;
typedef __attribute__((ext_vector_type(4))) float f32x4;

__device__ inline ushort f2bf(float f) {
    unsigned int u = __float_as_uint(f);
    u += 0x7fff + ((u >> 16) & 1);      // RNE
    return (ushort)(u >> 16);
}
__device__ inline float bf2f(ushort u) {
    return __uint_as_float(((unsigned int)u) << 16);
}

// ---------------- padding / transpose (emit bf16) ----------------

__global__ void pad_keys_kernel(const float* __restrict__ keys, ushort* __restrict__ kp) {
    int idx = blockIdx.x * blockDim.x + threadIdx.x;
    if (idx >= KP_SZ) return;
    int c = idx & 255;
    int r = (idx >> 8) % 514;
    int b = idx / (514 * 256);
    float v = 0.f;
    if (r >= 1 && r <= 512)
        v = keys[((size_t)b * 512 + (r - 1)) * 256 + c];
    kp[idx] = f2bf(v);
}

__global__ void pad_transpose_queries_kernel(const float* __restrict__ q, ushort* __restrict__ qp) {
    int idx = blockIdx.x * blockDim.x + threadIdx.x;
    if (idx >= QP_SZ) return;
    int c = idx % 80;
    int r = (idx / 80) % 2050;
    int b = idx / (2050 * 80);
    float v = 0.f;
    if (r >= 1 && r <= 2048)
        v = q[((size_t)b * 80 + c) * 2048 + (r - 1)];
    qp[idx] = f2bf(v);
}

// ---------------- weight transpose + bf16 (+ K zero-pad) ----------------
// wt[n*Kpad + k] = k < Kreal ? bf16(w[k*N + n]) : 0

__global__ void wtrans_kernel(const float* __restrict__ w, ushort* __restrict__ wt,
                              int Kreal, int Kpad, int N) {
    int idx = blockIdx.x * blockDim.x + threadIdx.x;
    if (idx >= N * Kpad) return;
    int k = idx % Kpad;
    int n = idx / Kpad;
    wt[idx] = (k < Kreal) ? f2bf(w[(size_t)k * N + n]) : (ushort)0;
}

// ---------------- bf16 MFMA conv-as-GEMM ----------------
// 256 threads = 4 waves; wave w: rows m0+w*16 .. +16, cols n0 .. n0+NFRAG*16.
// A: bf16, row m at A + (m/Tdim)*bStride + (m%Tdim)*rowStride, KPAD contiguous
//    (reads past Kreal hit neighbor data x zero weights = 0).
// Wt: [N][KPAD] bf16. C: [M][N] bf16.

template<int KPAD, int N, int NFRAG, bool RELU>
__global__ __launch_bounds__(256) void mfma_gemm(
    const ushort* __restrict__ A, const ushort* __restrict__ Wt,
    const float* __restrict__ bias, ushort* __restrict__ C,
    int Tdim, int bStride, int rowStride)
{
    const int tid  = threadIdx.x;
    const int wv   = tid >> 6;
    const int lane = tid & 63;
    const int lr   = lane & 15;
    const int lk   = lane >> 4;
    const int m0   = blockIdx.x * 64;
    const int n0   = blockIdx.y * (NFRAG * 16);

    const int m = m0 + wv * 16 + lr;
    const ushort* arow = A + (size_t)(m / Tdim) * bStride
                           + (size_t)(m % Tdim) * rowStride + lk * 8;
    const ushort* wtb  = Wt + (size_t)(n0 + lr) * KPAD + lk * 8;

    f32x4 acc[NFRAG];
    #pragma unroll
    for (int f = 0; f < NFRAG; ++f) acc[f] = (f32x4){0.f, 0.f, 0.f, 0.f};

    #pragma unroll
    for (int ks = 0; ks < KPAD / 32; ++ks) {
        const short8v a = *(const short8v*)(arow + ks * 32);
        #pragma unroll
        for (int f = 0; f < NFRAG; ++f) {
            const short8v b = *(const short8v*)(wtb + (size_t)f * 16 * KPAD + ks * 32);
            acc[f] = __builtin_amdgcn_mfma_f32_16x16x32_bf16(a, b, acc[f], 0, 0, 0);
        }
    }

    // C layout: col = lane&15 (N), row = (lane>>4)*4 + reg (M)
    const int orow = m0 + wv * 16 + lk * 4;
    #pragma unroll
    for (int f = 0; f < NFRAG; ++f) {
        const int col = n0 + f * 16 + lr;
        const float bv = bias[col];
        #pragma unroll
        for (int r = 0; r < 4; ++r) {
            float o = acc[f][r] + bv;
            if (RELU) o = fmaxf(o, 0.f);
            C[(size_t)(orow + r) * N + col] = f2bf(o);
        }
    }
}

// ---------------- k2t = -TEMP * sum(ke^2) (bf16 input) ----------------

__global__ void k2_kernel(const ushort* __restrict__ ke, float* __restrict__ k2) {
    int row = blockIdx.x * 4 + (threadIdx.x >> 6);   // (b*512 + t2)
    int lane = threadIdx.x & 63;
    ushort4 v = ((const ushort4*)(ke + (size_t)row * 256))[lane];
    float x = bf2f(v.x), y = bf2f(v.y), z = bf2f(v.z), w = bf2f(v.w);
    float ss = x * x + y * y + z * z + w * w;
    #pragma unroll
    for (int off = 32; off; off >>= 1) ss += __shfl_xor(ss, off);
    if (lane == 0) k2[row] = -TEMP * ss;
}

// ---------------- fused attention (round-5 verified) ----------------

__global__ __launch_bounds__(512) void attn_kernel(
    const ushort* __restrict__ qe, const ushort* __restrict__ ke,
    const float* __restrict__ k2t, const float* __restrict__ prior,
    const unsigned char* __restrict__ mask,
    float* __restrict__ out_attn, float* __restrict__ out_lp)
{
    __shared__ float S[16][516];
    __shared__ float rowZ[16];
    __shared__ float rowM[16];
    __shared__ float rowI[16];
    const int b    = blockIdx.x >> 7;
    const int t1_0 = (blockIdx.x & 127) << 4;
    const int tid  = threadIdx.x;
    const int lane = tid & 63;
    const int wv   = tid >> 6;

    // ---- phase 1: QK^T via MFMA, fold k2t ----
    {
        const int lr = lane & 15;
        const int lk = lane >> 4;
        const ushort* qrow = qe + ((size_t)b * TT1 + t1_0 + lr) * NATT + lk * 8;
        short8v a[8];
        #pragma unroll
        for (int k = 0; k < 8; ++k)
            a[k] = *(const short8v*)(qrow + k * 32);

        const ushort* kbase = ke + ((size_t)b * TT2 + wv * 64 + lr) * NATT + lk * 8;
        #pragma unroll
        for (int n = 0; n < 4; ++n) {
            f32x4 acc = {0.f, 0.f, 0.f, 0.f};
            const ushort* kb = kbase + (size_t)n * 16 * NATT;
            #pragma unroll
            for (int k = 0; k < 8; ++k) {
                short8v bfr = *(const short8v*)(kb + k * 32);
                acc = __builtin_amdgcn_mfma_f32_16x16x32_bf16(a[k], bfr, acc, 0, 0, 0);
            }
            const int col = wv * 64 + n * 16 + lr;
            const float k2v = k2t[(size_t)b * TT2 + col];
            #pragma unroll
            for (int r = 0; r < 4; ++r)
                S[lk * 4 + r][col] = fmaf(2.0f * TEMP, acc[r], k2v);
        }
    }
    __syncthreads();

    const int rr = tid >> 5;
    const int jj = tid & 31;

    // ---- phase 2a: logZ per row ----
    {
        float sv[16];
        #pragma unroll
        for (int k = 0; k < 16; ++k) sv[k] = S[rr][jj + 32 * k];
        float mx = sv[0];
        #pragma unroll
        for (int k = 1; k < 16; ++k) mx = fmaxf(mx, sv[k]);
        #pragma unroll
        for (int off = 16; off; off >>= 1) mx = fmaxf(mx, __shfl_xor(mx, off));
        float se = 0.f;
        #pragma unroll
        for (int k = 0; k < 16; ++k) se += __expf(sv[k] - mx);
        #pragma unroll
        for (int off = 16; off; off >>= 1) se += __shfl_xor(se, off);
        if (jj == 0) rowZ[rr] = mx + __logf(se);
    }
    __syncthreads();

    // ---- phase 2b: lp store, U (masked) -> LDS ----
    const int t2 = tid;
    {
        const bool mv = mask[(size_t)b * TT2 + t2] != 0;
        const float* prow = prior + ((size_t)b * TT2 + t2) * TT1 + t1_0;
        #pragma unroll
        for (int g = 0; g < 4; ++g) {
            float4 p4 = ((const float4*)prow)[g];
            float pp[4] = {p4.x, p4.y, p4.z, p4.w};
            #pragma unroll
            for (int q = 0; q < 4; ++q) {
                const int r = g * 4 + q;
                const float sc = S[r][t2];
                const float uu = sc + __logf(pp[q] + 1e-8f);
                out_lp[((size_t)b * TT1 + t1_0 + r) * TT2 + t2] = uu - rowZ[r];
                S[r][t2] = mv ? -INFINITY : uu;
            }
        }
    }
    __syncthreads();

    // ---- phase 2c: masked max + inv-sumexp per row ----
    {
        float uv[16];
        #pragma unroll
        for (int k = 0; k < 16; ++k) uv[k] = S[rr][jj + 32 * k];
        float mx = uv[0];
        #pragma unroll
        for (int k = 1; k < 16; ++k) mx = fmaxf(mx, uv[k]);
        #pragma unroll
        for (int off = 16; off; off >>= 1) mx = fmaxf(mx, __shfl_xor(mx, off));
        float se = 0.f;
        #pragma unroll
        for (int k = 0; k < 16; ++k) se += __expf(uv[k] - mx);
        #pragma unroll
        for (int off = 16; off; off >>= 1) se += __shfl_xor(se, off);
        if (jj == 0) { rowM[rr] = mx; rowI[rr] = 1.0f / se; }
    }
    __syncthreads();

    // ---- phase 2d: attn = exp(U - m2) * inv ----
    #pragma unroll
    for (int r = 0; r < 16; ++r) {
        const float a = __expf(S[r][t2] - rowM[r]) * rowI[r];
        out_attn[((size_t)b * TT1 + t1_0 + r) * TT2 + t2] = a;
    }
}

// ---------------- launch ----------------

extern "C" void kernel_launch(void* const* d_in, const int* in_sizes, int n_in,
                              void* d_out, int out_size, void* d_ws, size_t ws_size,
                              hipStream_t stream) {
    const float* queries = (const float*)d_in[0];   // (B, 80, 2048)
    const float* keys    = (const float*)d_in[1];   // (B, 512, 256)
    const unsigned char* mask = (const unsigned char*)d_in[2]; // (B, 512) bool
    const float* prior   = (const float*)d_in[3];   // (B, 512, 2048)
    const float* kw1 = (const float*)d_in[4];
    const float* kb1 = (const float*)d_in[5];
    const float* kw2 = (const float*)d_in[6];
    const float* kb2 = (const float*)d_in[7];
    const float* qw1 = (const float*)d_in[8];
    const float* qb1 = (const float*)d_in[9];
    const float* qw2 = (const float*)d_in[10];
    const float* qb2 = (const float*)d_in[11];
    const float* qw3 = (const float*)d_in[12];
    const float* qb3 = (const float*)d_in[13];

    ushort* us   = (ushort*)d_ws;
    ushort* kp   = us;
    ushort* h1   = kp  + KP_SZ;
    ushort* ke   = h1  + H1_SZ;
    ushort* qp   = ke  + KE_SZ;
    ushort* qh1  = qp  + QP_SZ;
    ushort* qh2  = qh1 + QH1_SZ;
    ushort* qe   = qh2 + QH2_SZ;
    ushort* w1t  = qe  + QE_SZ;
    ushort* w2t  = w1t + W1T_SZ;
    ushort* w3t  = w2t + W2T_SZ;
    ushort* w4t  = w3t + W3T_SZ;
    ushort* w5t  = w4t + W4T_SZ;
    float*  k2   = (float*)(w5t + W5T_SZ);

    float* out_attn = (float*)d_out;
    float* out_lp   = out_attn + (size_t)NB * TT1 * TT2;

    // input prep
    pad_keys_kernel<<<KP_SZ / 256, 256, 0, stream>>>(keys, kp);
    pad_transpose_queries_kernel<<<QP_SZ / 256, 256, 0, stream>>>(queries, qp);
    wtrans_kernel<<<(W1T_SZ + 255) / 256, 256, 0, stream>>>(kw1, w1t, 768, 768, 512);
    wtrans_kernel<<<(W2T_SZ + 255) / 256, 256, 0, stream>>>(kw2, w2t, 512, 512, 256);
    wtrans_kernel<<<(W3T_SZ + 255) / 256, 256, 0, stream>>>(qw1, w3t, 240, 256, 160);
    wtrans_kernel<<<(W4T_SZ + 255) / 256, 256, 0, stream>>>(qw2, w4t, 160, 160, 80);
    wtrans_kernel<<<(W5T_SZ + 255) / 256, 256, 0, stream>>>(qw3, w5t, 80, 96, 256);

    // key path
    mfma_gemm<768, 512, 4, true><<<dim3(128, 8), 256, 0, stream>>>(
        kp, w1t, kb1, h1, 512, 514 * 256, 256);
    mfma_gemm<512, 256, 4, false><<<dim3(128, 4), 256, 0, stream>>>(
        h1, w2t, kb2, ke, 512, 512 * 512, 512);
    k2_kernel<<<(NB * 512) / 4, 256, 0, stream>>>(ke, k2);

    // query path
    mfma_gemm<256, 160, 10, true><<<dim3(512, 1), 256, 0, stream>>>(
        qp, w3t, qb1, qh1, 2048, 2050 * 80, 80);
    mfma_gemm<160, 80, 5, true><<<dim3(512, 1), 256, 0, stream>>>(
        qh1, w4t, qb2, qh2, 2048, 2048 * 160, 160);
    mfma_gemm<96, 256, 4, false><<<dim3(512, 4), 256, 0, stream>>>(
        qh2, w5t, qb3, qe, 2048, 2048 * 80, 80);

    // fused attention
    attn_kernel<<<NB * (TT1 / 16), 512, 0, stream>>>(
        qe, ke, k2, prior, mask, out_attn, out_lp);
}

// Round 8
// 242.987 us; speedup vs baseline: 2.5024x; 1.0415x over previous
//
#include <hip/hip_runtime.h>
#include <cmath>

#define NB    16
#define TT1   2048
#define TT2   512
#define NATT  256
#define TEMP  0.0005f

// workspace element counts (ushort = bf16 unless noted)
#define KP_SZ   (NB*514*256)        // padded keys (B, 514, 256)
#define H1_SZ   (NB*512*512)        // key conv1 out (relu)
#define KE_SZ   (NB*512*256)        // key proj out
#define QP_SZ   (NB*2050*80)        // padded transposed queries
#define QH1_SZ  (NB*2048*160)
#define QH2_SZ  (NB*2048*80)
#define QE_SZ   (NB*2048*256)
#define W1T_SZ  (512*768)
#define W2T_SZ  (256*512)
#define W3T_SZ  (160*256)
#define W4T_SZ  (80*160)
#define W5T_SZ  (256*96)
#define LGP_SZ  (NB*TT1*TT2)        // bf16 log(prior+eps), transposed [b][t1][t2]
#define K2_SZ   (NB*512)            // f32

typedef __attribute__((ext_vector_type(8))) short short8v;
typedef __attribute__((ext_vector_type(4))) float f32x4;

__device__ inline ushort f2bf(float f) {
    unsigned int u = __float_as_uint(f);
    u += 0x7fff + ((u >> 16) & 1);      // RNE
    return (ushort)(u >> 16);
}
__device__ inline float bf2f(ushort u) {
    return __uint_as_float(((unsigned int)u) << 16);
}

// ---------------- padding / transpose (emit bf16) ----------------

__global__ void pad_keys_kernel(const float* __restrict__ keys, ushort* __restrict__ kp) {
    int idx = blockIdx.x * blockDim.x + threadIdx.x;
    if (idx >= KP_SZ) return;
    int c = idx & 255;
    int r = (idx >> 8) % 514;
    int b = idx / (514 * 256);
    float v = 0.f;
    if (r >= 1 && r <= 512)
        v = keys[((size_t)b * 512 + (r - 1)) * 256 + c];
    kp[idx] = f2bf(v);
}

__global__ void pad_transpose_queries_kernel(const float* __restrict__ q, ushort* __restrict__ qp) {
    int idx = blockIdx.x * blockDim.x + threadIdx.x;
    if (idx >= QP_SZ) return;
    int c = idx % 80;
    int r = (idx / 80) % 2050;
    int b = idx / (2050 * 80);
    float v = 0.f;
    if (r >= 1 && r <= 2048)
        v = q[((size_t)b * 80 + c) * 2048 + (r - 1)];
    qp[idx] = f2bf(v);
}

// ---------------- prior: transpose + log -> bf16 ----------------
// lgp[b][t1][t2] = bf16(log(prior[b][t2][t1] + 1e-8))

__global__ __launch_bounds__(256) void prior_log_transpose(
    const float* __restrict__ prior, ushort* __restrict__ lgp)
{
    __shared__ float T[64][65];
    const int b    = blockIdx.z;
    const int t1_0 = blockIdx.x * 64;
    const int t2_0 = blockIdx.y * 64;
    const int j  = threadIdx.x & 63;
    const int i0 = (threadIdx.x >> 6) * 16;
    #pragma unroll
    for (int r = 0; r < 16; ++r)
        T[i0 + r][j] = prior[((size_t)b * TT2 + t2_0 + i0 + r) * TT1 + t1_0 + j];
    __syncthreads();
    #pragma unroll
    for (int r = 0; r < 16; ++r) {
        const int p = i0 + r;
        const float v = T[j][p];
        lgp[((size_t)b * TT1 + t1_0 + p) * TT2 + t2_0 + j] = f2bf(__logf(v + 1e-8f));
    }
}

// ---------------- weight transpose + bf16 (+ K zero-pad) ----------------

__global__ void wtrans_kernel(const float* __restrict__ w, ushort* __restrict__ wt,
                              int Kreal, int Kpad, int N) {
    int idx = blockIdx.x * blockDim.x + threadIdx.x;
    if (idx >= N * Kpad) return;
    int k = idx % Kpad;
    int n = idx / Kpad;
    wt[idx] = (k < Kreal) ? f2bf(w[(size_t)k * N + n]) : (ushort)0;
}

// ---------------- bf16 MFMA conv-as-GEMM ----------------
// 256 threads = 4 waves; wave wv: rows m0 + wv*MFRAG*16 .. +MFRAG*16,
// cols n0 .. n0+NFRAG*16. B-fragments shared across MFRAG row-frags.

template<int KPAD, int N, int MFRAG, int NFRAG, bool RELU>
__global__ __launch_bounds__(256) void mfma_gemm(
    const ushort* __restrict__ A, const ushort* __restrict__ Wt,
    const float* __restrict__ bias, ushort* __restrict__ C,
    int Tdim, int bStride, int rowStride)
{
    const int tid  = threadIdx.x;
    const int wv   = tid >> 6;
    const int lane = tid & 63;
    const int lr   = lane & 15;
    const int lk   = lane >> 4;
    const int m0   = blockIdx.x * (64 * MFRAG);
    const int n0   = blockIdx.y * (NFRAG * 16);

    const ushort* arow[MFRAG];
    #pragma unroll
    for (int mf = 0; mf < MFRAG; ++mf) {
        const int m = m0 + (wv * MFRAG + mf) * 16 + lr;
        arow[mf] = A + (size_t)(m / Tdim) * bStride
                     + (size_t)(m % Tdim) * rowStride + lk * 8;
    }
    const ushort* wtb = Wt + (size_t)(n0 + lr) * KPAD + lk * 8;

    f32x4 acc[MFRAG][NFRAG];
    #pragma unroll
    for (int mf = 0; mf < MFRAG; ++mf)
        #pragma unroll
        for (int f = 0; f < NFRAG; ++f) acc[mf][f] = (f32x4){0.f, 0.f, 0.f, 0.f};

    #pragma unroll
    for (int ks = 0; ks < KPAD / 32; ++ks) {
        short8v a[MFRAG];
        #pragma unroll
        for (int mf = 0; mf < MFRAG; ++mf)
            a[mf] = *(const short8v*)(arow[mf] + ks * 32);
        #pragma unroll
        for (int f = 0; f < NFRAG; ++f) {
            const short8v b = *(const short8v*)(wtb + (size_t)f * 16 * KPAD + ks * 32);
            #pragma unroll
            for (int mf = 0; mf < MFRAG; ++mf)
                acc[mf][f] = __builtin_amdgcn_mfma_f32_16x16x32_bf16(a[mf], b, acc[mf][f], 0, 0, 0);
        }
    }

    // C layout: col = lane&15 (N), row = (lane>>4)*4 + reg (M)
    #pragma unroll
    for (int mf = 0; mf < MFRAG; ++mf) {
        const int orow = m0 + (wv * MFRAG + mf) * 16 + lk * 4;
        #pragma unroll
        for (int f = 0; f < NFRAG; ++f) {
            const int col = n0 + f * 16 + lr;
            const float bv = bias[col];
            #pragma unroll
            for (int r = 0; r < 4; ++r) {
                float o = acc[mf][f][r] + bv;
                if (RELU) o = fmaxf(o, 0.f);
                C[(size_t)(orow + r) * N + col] = f2bf(o);
            }
        }
    }
}

// ---------------- k2t = -TEMP * sum(ke^2) (bf16 input) ----------------

__global__ void k2_kernel(const ushort* __restrict__ ke, float* __restrict__ k2) {
    int row = blockIdx.x * 4 + (threadIdx.x >> 6);   // (b*512 + t2)
    int lane = threadIdx.x & 63;
    ushort4 v = ((const ushort4*)(ke + (size_t)row * 256))[lane];
    float x = bf2f(v.x), y = bf2f(v.y), z = bf2f(v.z), w = bf2f(v.w);
    float ss = x * x + y * y + z * z + w * w;
    #pragma unroll
    for (int off = 32; off; off >>= 1) ss += __shfl_xor(ss, off);
    if (lane == 0) k2[row] = -TEMP * ss;
}

// ---------------- fused attention ----------------
// phase 1 : wave w computes s = 2*TEMP*QK^T + k2t -> LDS S
// phase 2a: row-layout (32 thr/row) reduce -> logZ[r]
// phase 2b: t2-layout: u = s + lg(prefetched), lp = u - logZ, U -> LDS (masked)
// phase 2c: row-layout reduce -> m2[r], inv[r]
// phase 2d: t2-layout: attn = exp(U - m2) * inv

__global__ __launch_bounds__(512) void attn_kernel(
    const ushort* __restrict__ qe, const ushort* __restrict__ ke,
    const float* __restrict__ k2t, const ushort* __restrict__ lgp,
    const unsigned char* __restrict__ mask,
    float* __restrict__ out_attn, float* __restrict__ out_lp)
{
    __shared__ float S[16][516];
    __shared__ float rowZ[16];
    __shared__ float rowM[16];
    __shared__ float rowI[16];
    const int b    = blockIdx.x >> 7;
    const int t1_0 = (blockIdx.x & 127) << 4;
    const int tid  = threadIdx.x;
    const int lane = tid & 63;
    const int wv   = tid >> 6;
    const int t2   = tid;

    // ---- prefetch (issued before MFMA phase; used after barriers) ----
    const bool mv = mask[(size_t)b * TT2 + t2] != 0;
    ushort lg[16];
    #pragma unroll
    for (int r = 0; r < 16; ++r)
        lg[r] = lgp[((size_t)b * TT1 + t1_0 + r) * TT2 + t2];

    // ---- phase 1: QK^T via MFMA, fold k2t ----
    {
        const int lr = lane & 15;
        const int lk = lane >> 4;
        const ushort* qrow = qe + ((size_t)b * TT1 + t1_0 + lr) * NATT + lk * 8;
        short8v a[8];
        #pragma unroll
        for (int k = 0; k < 8; ++k)
            a[k] = *(const short8v*)(qrow + k * 32);

        const ushort* kbase = ke + ((size_t)b * TT2 + wv * 64 + lr) * NATT + lk * 8;
        #pragma unroll
        for (int n = 0; n < 4; ++n) {
            f32x4 acc = {0.f, 0.f, 0.f, 0.f};
            const ushort* kb = kbase + (size_t)n * 16 * NATT;
            #pragma unroll
            for (int k = 0; k < 8; ++k) {
                short8v bfr = *(const short8v*)(kb + k * 32);
                acc = __builtin_amdgcn_mfma_f32_16x16x32_bf16(a[k], bfr, acc, 0, 0, 0);
            }
            const int col = wv * 64 + n * 16 + lr;
            const float k2v = k2t[(size_t)b * TT2 + col];
            #pragma unroll
            for (int r = 0; r < 4; ++r)
                S[lk * 4 + r][col] = fmaf(2.0f * TEMP, acc[r], k2v);
        }
    }
    __syncthreads();

    const int rr = tid >> 5;
    const int jj = tid & 31;

    // ---- phase 2a: logZ per row ----
    {
        float sv[16];
        #pragma unroll
        for (int k = 0; k < 16; ++k) sv[k] = S[rr][jj + 32 * k];
        float mx = sv[0];
        #pragma unroll
        for (int k = 1; k < 16; ++k) mx = fmaxf(mx, sv[k]);
        #pragma unroll
        for (int off = 16; off; off >>= 1) mx = fmaxf(mx, __shfl_xor(mx, off));
        float se = 0.f;
        #pragma unroll
        for (int k = 0; k < 16; ++k) se += __expf(sv[k] - mx);
        #pragma unroll
        for (int off = 16; off; off >>= 1) se += __shfl_xor(se, off);
        if (jj == 0) rowZ[rr] = mx + __logf(se);
    }
    __syncthreads();

    // ---- phase 2b: lp store, U (masked) -> LDS ----
    #pragma unroll
    for (int r = 0; r < 16; ++r) {
        const float uu = S[r][t2] + bf2f(lg[r]);
        out_lp[((size_t)b * TT1 + t1_0 + r) * TT2 + t2] = uu - rowZ[r];
        S[r][t2] = mv ? -INFINITY : uu;
    }
    __syncthreads();

    // ---- phase 2c: masked max + inv-sumexp per row ----
    {
        float uv[16];
        #pragma unroll
        for (int k = 0; k < 16; ++k) uv[k] = S[rr][jj + 32 * k];
        float mx = uv[0];
        #pragma unroll
        for (int k = 1; k < 16; ++k) mx = fmaxf(mx, uv[k]);
        #pragma unroll
        for (int off = 16; off; off >>= 1) mx = fmaxf(mx, __shfl_xor(mx, off));
        float se = 0.f;
        #pragma unroll
        for (int k = 0; k < 16; ++k) se += __expf(uv[k] - mx);
        #pragma unroll
        for (int off = 16; off; off >>= 1) se += __shfl_xor(se, off);
        if (jj == 0) { rowM[rr] = mx; rowI[rr] = 1.0f / se; }
    }
    __syncthreads();

    // ---- phase 2d: attn = exp(U - m2) * inv ----
    #pragma unroll
    for (int r = 0; r < 16; ++r) {
        const float a = __expf(S[r][t2] - rowM[r]) * rowI[r];
        out_attn[((size_t)b * TT1 + t1_0 + r) * TT2 + t2] = a;
    }
}

// ---------------- launch ----------------

extern "C" void kernel_launch(void* const* d_in, const int* in_sizes, int n_in,
                              void* d_out, int out_size, void* d_ws, size_t ws_size,
                              hipStream_t stream) {
    const float* queries = (const float*)d_in[0];   // (B, 80, 2048)
    const float* keys    = (const float*)d_in[1];   // (B, 512, 256)
    const unsigned char* mask = (const unsigned char*)d_in[2]; // (B, 512) bool
    const float* prior   = (const float*)d_in[3];   // (B, 512, 2048)
    const float* kw1 = (const float*)d_in[4];
    const float* kb1 = (const float*)d_in[5];
    const float* kw2 = (const float*)d_in[6];
    const float* kb2 = (const float*)d_in[7];
    const float* qw1 = (const float*)d_in[8];
    const float* qb1 = (const float*)d_in[9];
    const float* qw2 = (const float*)d_in[10];
    const float* qb2 = (const float*)d_in[11];
    const float* qw3 = (const float*)d_in[12];
    const float* qb3 = (const float*)d_in[13];

    ushort* us   = (ushort*)d_ws;
    ushort* kp   = us;
    ushort* h1   = kp  + KP_SZ;
    ushort* ke   = h1  + H1_SZ;
    ushort* qp   = ke  + KE_SZ;
    ushort* qh1  = qp  + QP_SZ;
    ushort* qh2  = qh1 + QH1_SZ;
    ushort* qe   = qh2 + QH2_SZ;
    ushort* w1t  = qe  + QE_SZ;
    ushort* w2t  = w1t + W1T_SZ;
    ushort* w3t  = w2t + W2T_SZ;
    ushort* w4t  = w3t + W3T_SZ;
    ushort* w5t  = w4t + W4T_SZ;
    ushort* lgp  = w5t + W5T_SZ;
    float*  k2   = (float*)(lgp + LGP_SZ);

    float* out_attn = (float*)d_out;
    float* out_lp   = out_attn + (size_t)NB * TT1 * TT2;

    // input prep
    prior_log_transpose<<<dim3(TT1 / 64, TT2 / 64, NB), 256, 0, stream>>>(prior, lgp);
    pad_keys_kernel<<<KP_SZ / 256, 256, 0, stream>>>(keys, kp);
    pad_transpose_queries_kernel<<<QP_SZ / 256, 256, 0, stream>>>(queries, qp);
    wtrans_kernel<<<(W1T_SZ + 255) / 256, 256, 0, stream>>>(kw1, w1t, 768, 768, 512);
    wtrans_kernel<<<(W2T_SZ + 255) / 256, 256, 0, stream>>>(kw2, w2t, 512, 512, 256);
    wtrans_kernel<<<(W3T_SZ + 255) / 256, 256, 0, stream>>>(qw1, w3t, 240, 256, 160);
    wtrans_kernel<<<(W4T_SZ + 255) / 256, 256, 0, stream>>>(qw2, w4t, 160, 160, 80);
    wtrans_kernel<<<(W5T_SZ + 255) / 256, 256, 0, stream>>>(qw3, w5t, 80, 96, 256);

    // key path
    mfma_gemm<768, 512, 2, 4, true><<<dim3(64, 8), 256, 0, stream>>>(
        kp, w1t, kb1, h1, 512, 514 * 256, 256);
    mfma_gemm<512, 256, 2, 4, false><<<dim3(64, 4), 256, 0, stream>>>(
        h1, w2t, kb2, ke, 512, 512 * 512, 512);
    k2_kernel<<<(NB * 512) / 4, 256, 0, stream>>>(ke, k2);

    // query path
    mfma_gemm<256, 160, 2, 10, true><<<dim3(256, 1), 256, 0, stream>>>(
        qp, w3t, qb1, qh1, 2048, 2050 * 80, 80);
    mfma_gemm<160, 80, 2, 5, true><<<dim3(256, 1), 256, 0, stream>>>(
        qh1, w4t, qb2, qh2, 2048, 2048 * 160, 160);
    mfma_gemm<96, 256, 2, 4, false><<<dim3(256, 4), 256, 0, stream>>>(
        qh2, w5t, qb3, qe, 2048, 2048 * 80, 80);

    // fused attention
    attn_kernel<<<NB * (TT1 / 16), 512, 0, stream>>>(
        qe, ke, k2, lgp, mask, out_attn, out_lp);
}